// Round 10
// baseline (44.757 us; speedup 1.0000x reference)
//
#include <hip/hip_runtime.h>
#include <hip/hip_fp16.h>

#define B_ 4
#define F_ 2
#define C_ 16
#define H_ 48
#define W_ 160
#define D_ 96
#define HW_ (H_*W_)
#define PIX_ 64            // pixels per block (one wave = 64 px at one depth-group)
#define GRP_ 16            // depth groups per block (PIX_*GRP_ = 1024 threads)
#define BINS_ (D_/GRP_)    // 6 bins per group
#define NCHUNK_ (HW_/PIX_) // 120

// Prep: mats (block 0) + transpose/fp16 of cur and look.
// 2 threads per pixel (8 channels each) -> 720 blocks for TLP.
__global__ __launch_bounds__(256) void prep_kernel(
    const float* __restrict__ cur, const float* __restrict__ look,
    const float* __restrict__ poses, const float* __restrict__ Kmat,
    __half* __restrict__ curH, __half* __restrict__ lookH,
    float* __restrict__ mats)
{
  int tid = threadIdx.x;
  int bid = blockIdx.x;
  if (bid == 0 && tid < B_*F_) {
    int t = tid, b = t / F_;
    const float* T  = poses + t*16;
    const float* Kb = Kmat + b*16;
    float sum = 0.f;
    #pragma unroll
    for (int i = 0; i < 16; ++i) sum += T[i];
    #pragma unroll
    for (int i = 0; i < 3; ++i) {
      #pragma unroll
      for (int j = 0; j < 4; ++j) {
        float v = 0.f;
        #pragma unroll
        for (int k = 0; k < 4; ++k) v += Kb[i*4+k] * T[k*4+j];
        mats[t*16 + i*4 + j] = v;
      }
    }
    mats[t*16 + 12] = (sum != 0.f) ? 1.f : 0.f;
  }
  // 256 threads = 128 pixels x 2 halves; wave-uniform half -> coalesced loads.
  int px_l = tid & 127;
  int h    = tid >> 7;                 // 0 or 1 (channel half)
  int gp   = bid*128 + px_l;           // global pixel id over cur then look
  const float* src;
  __half* dst;
  int hw, c0 = h*8;
  if (gp < B_*HW_) {
    hw = gp % HW_;
    int s = gp / HW_;
    src = cur + (size_t)s*C_*HW_ + hw;
    dst = curH + (size_t)gp*C_ + c0;
  } else {
    int j = gp - B_*HW_;
    hw = j % HW_;
    int s = j / HW_;
    src = look + (size_t)s*C_*HW_ + hw;
    dst = lookH + (size_t)j*C_ + c0;
  }
  __half2 hh[4];
  #pragma unroll
  for (int j = 0; j < 4; ++j)
    hh[j] = __floats2half2_rn(src[(size_t)(c0+2*j)*HW_], src[(size_t)(c0+2*j+1)*HW_]);
  *reinterpret_cast<uint4*>(dst) = *reinterpret_cast<uint4*>(&hh[0]);
}

// Fused cost + finalize. Block = 64 pixels x 16 depth-groups (6 bins each)
// = all 96 bins of one 64-pixel strip in one block. Frame-OUTER loop so the
// block's concurrent gather footprint is one frame's ~30KB region (L1-fit).
// No conditional tap state (rounds 6-8 lesson): 8 unconditional loads/bin.
__global__ __launch_bounds__(1024, 4) void fused_kernel(
    const __half* __restrict__ curH, const __half* __restrict__ lookH,
    const float* __restrict__ mats, const float* __restrict__ invK,
    const float* __restrict__ dbins,
    float* __restrict__ cost, float* __restrict__ missing)
{
  int tid = threadIdx.x;
  int pix = tid & (PIX_-1);
  int grp = tid >> 6;                 // 0..15 (wave index)
  int bid = blockIdx.x;
  int chunk = bid % NCHUNK_;
  int b = bid / NCHUNK_;
  int hw = chunk*PIX_ + pix;
  int x = hw % W_, y = hw / W_;
  size_t obase = ((size_t)(b*D_ + grp*BINS_))*HW_ + hw;

  float res[BINS_];
  #pragma unroll
  for (int dd = 0; dd < BINS_; ++dd) res[dd] = 0.f;
  float lmax = 0.f;
  bool interior = (x >= 2 && x < W_-2 && y >= 2 && y < H_-2);
  if (interior) {
    const float* iK = invK + b*16;
    float xf = (float)x, yf = (float)y;
    float r0 = iK[0]*xf + iK[1]*yf + iK[2];
    float r1 = iK[4]*xf + iK[5]*yf + iK[6];
    float r2 = iK[8]*xf + iK[9]*yf + iK[10];
    __half2 cc2[8];
    {
      const uint4* cur4 = reinterpret_cast<const uint4*>(curH + (size_t)(b*HW_ + hw)*C_);
      *reinterpret_cast<uint4*>(&cc2[0]) = cur4[0];
      *reinterpret_cast<uint4*>(&cc2[4]) = cur4[1];
    }
    float diffs0[BINS_];
    #pragma unroll
    for (int f = 0; f < F_; ++f) {
      const float* Mt = mats + (b*F_+f)*16;
      float M0=Mt[0], M1=Mt[1], M2 =Mt[2],  M3 =Mt[3];
      float M4=Mt[4], M5=Mt[5], M6 =Mt[6],  M7 =Mt[7];
      float M8=Mt[8], M9=Mt[9], M10=Mt[10], M11=Mt[11];
      float valid = Mt[12];
      const __half* fbase = lookH + (size_t)((b*F_+f)*HW_)*C_;
      #pragma unroll
      for (int dd = 0; dd < BINS_; ++dd) {
        float dep = dbins[grp*BINS_ + dd];
        float p0 = dep*r0, p1 = dep*r1, p2 = dep*r2;
        float camx = M0*p0 + M1*p1 + M2 *p2 + M3;
        float camy = M4*p0 + M5*p1 + M6 *p2 + M7;
        float camz = M8*p0 + M9*p1 + M10*p2 + M11;
        float z  = camz + 1e-7f;
        float px = camx / z;
        float py = camy / z;
        bool ok = (valid != 0.f) && (px >= 2.f) && (px <= (float)(W_-2))
                                 && (py >= 2.f) && (py <= (float)(H_-2));
        float x0 = floorf(px), y0 = floorf(py);
        float fx = px - x0, fy = py - y0;
        fx = fminf(fmaxf(fx, 0.f), 1.f);
        fy = fminf(fmaxf(fy, 0.f), 1.f);
        int xi = min(max((int)x0, 0), W_-2);
        int yi = min(max((int)y0, 0), H_-2);
        const __half* base = fbase + ((size_t)(yi*W_ + xi))*C_;
        // batched unconditional 8x16B tap loads
        uint4 t[8];
        {
          const uint4* rr0 = reinterpret_cast<const uint4*>(base);
          const uint4* rr1 = reinterpret_cast<const uint4*>(base + W_*C_);
          #pragma unroll
          for (int i = 0; i < 4; ++i) t[i]   = rr0[i];
          #pragma unroll
          for (int i = 0; i < 4; ++i) t[4+i] = rr1[i];
        }
        __half2 w00h = __float2half2_rn((1.f-fx)*(1.f-fy));
        __half2 w10h = __float2half2_rn(fx*(1.f-fy));
        __half2 w01h = __float2half2_rn((1.f-fx)*fy);
        __half2 w11h = __float2half2_rn(fx*fy);
        const __half2* a00 = reinterpret_cast<const __half2*>(&t[0]);
        const __half2* a10 = reinterpret_cast<const __half2*>(&t[2]);
        const __half2* a01 = reinterpret_cast<const __half2*>(&t[4]);
        const __half2* a11 = reinterpret_cast<const __half2*>(&t[6]);
        __half2 acc0 = __float2half2_rn(0.f);
        __half2 acc1 = __float2half2_rn(0.f);
        #pragma unroll
        for (int i = 0; i < 8; ++i) {
          __half2 v = __hmul2(w00h, a00[i]);
          v = __hfma2(w10h, a10[i], v);
          v = __hfma2(w01h, a01[i], v);
          v = __hfma2(w11h, a11[i], v);
          __half2 dsub = __habs2(__hsub2(v, cc2[i]));
          if (i & 1) acc1 = __hadd2(acc1, dsub);
          else       acc0 = __hadd2(acc0, dsub);
        }
        float2 f0 = __half22float2(acc0);
        float2 f1 = __half22float2(acc1);
        float s = (f0.x + f0.y) + (f1.x + f1.y);
        float diffs = s * (1.f/16.f);
        diffs = ok ? diffs : 0.f;
        if (f == 0) {
          diffs0[dd] = diffs;
        } else {
          float c0v = diffs0[dd];
          float cnt = ((c0v > 0.f) ? 1.f : 0.f) + ((diffs > 0.f) ? 1.f : 0.f);
          float r = (c0v + diffs) / (cnt + 1e-7f);
          res[dd] = r;
          lmax = fmaxf(lmax, r);
        }
      }
    }
  }

  // per-pixel max over the 16 depth-groups
  __shared__ float lmaxs[GRP_][PIX_];
  lmaxs[grp][pix] = lmax;
  __syncthreads();
  float pmax = lmaxs[0][pix];
  #pragma unroll
  for (int g = 1; g < GRP_; ++g) pmax = fmaxf(pmax, lmaxs[g][pix]);

  // write cost (missing-filled) + missing, straight from registers
  #pragma unroll
  for (int dd = 0; dd < BINS_; ++dd) {
    size_t o = obase + (size_t)dd*HW_;
    float v = res[dd];
    float miss = (v == 0.f) ? 1.f : 0.f;
    cost[o]    = miss ? pmax : v;
    missing[o] = miss;
  }
}

extern "C" void kernel_launch(void* const* d_in, const int* in_sizes, int n_in,
                              void* d_out, int out_size, void* d_ws, size_t ws_size,
                              hipStream_t stream) {
  const float* cur   = (const float*)d_in[0];
  const float* look  = (const float*)d_in[1];
  const float* poses = (const float*)d_in[2];
  const float* Km    = (const float*)d_in[3];
  const float* invK  = (const float*)d_in[4];
  const float* dbins = (const float*)d_in[5];

  float* out_cost = (float*)d_out;
  float* out_miss = out_cost + (size_t)B_*D_*HW_;

  char*   ws    = (char*)d_ws;
  float*  mats  = (float*)ws;                                       // 128 floats
  __half* curH  = (__half*)(ws + 1024);                             // B*HW*C f16
  __half* lookH = (__half*)(ws + 1024 + (size_t)B_*HW_*C_*2);       // B*F*HW*C f16

  prep_kernel<<<(B_*HW_ + B_*F_*HW_)/128, 256, 0, stream>>>(
      cur, look, poses, Km, curH, lookH, mats);
  fused_kernel<<<B_*NCHUNK_, 1024, 0, stream>>>(
      curH, lookH, mats, invK, dbins, out_cost, out_miss);
}